// Round 7
// baseline (123.313 us; speedup 1.0000x reference)
//
#include <hip/hip_runtime.h>

#define N_NODES 100000
#define N_EDGES 3200000
#define NB 782              // buckets of 128 nodes
#define NBP 1024            // padded bins for scan
#define NHB 256             // binning blocks / regions
#define EPB (N_EDGES / NHB) // 12500 edges per region (exact)
#define BSB 512             // binning block threads
#define BS 256              // consumer block threads
#define CAP 8192            // LDS stage capacity (words); bucket avg ~4092

typedef unsigned char u8;

// ---------- binning: per-block LDS counting sort, linear flush ----------
// binned block-major: region blk owns binned[blk*EPB ..). runinfo[blk*NB+b] =
// off | (cnt<<16). packed edge = (src<<7)|(dst&127). binned_b = dst&127 bytes.
__global__ __launch_bounds__(BSB) void k_bin2(const int* __restrict__ src,
                                              const int* __restrict__ dst,
                                              unsigned* __restrict__ binned,
                                              u8* __restrict__ binned_b,
                                              unsigned* __restrict__ runinfo) {
    __shared__ int hist[NBP];
    __shared__ int scanv[NBP];
    __shared__ int sh[BSB];
    __shared__ alignas(16) unsigned stage[EPB];
    int t = threadIdx.x, blk = blockIdx.x;
    for (int b = t; b < NBP; b += BSB) hist[b] = 0;
    __syncthreads();
    int base = blk * EPB;
    for (int i = t * 4; i < EPB; i += BSB * 4) {
        int4 d = *(const int4*)(dst + base + i);
        atomicAdd(&hist[d.x >> 7], 1);
        atomicAdd(&hist[d.y >> 7], 1);
        atomicAdd(&hist[d.z >> 7], 1);
        atomicAdd(&hist[d.w >> 7], 1);
    }
    __syncthreads();
    int b0 = hist[2 * t], b1 = hist[2 * t + 1];
    int v = b0 + b1;
    sh[t] = v;
    __syncthreads();
    for (int off = 1; off < BSB; off <<= 1) {
        int u = (t >= off) ? sh[t - off] : 0;
        __syncthreads();
        sh[t] += u;
        __syncthreads();
    }
    int excl = sh[t] - v;
    scanv[2 * t] = excl;
    scanv[2 * t + 1] = excl + b0;
    __syncthreads();
    for (int b = t; b < NB; b += BSB)
        runinfo[(size_t)blk * NB + b] =
            (unsigned)scanv[b] | ((unsigned)hist[b] << 16);
    __syncthreads();
    for (int i = t * 4; i < EPB; i += BSB * 4) {
        int4 s4 = *(const int4*)(src + base + i);
        int4 d4 = *(const int4*)(dst + base + i);
        int p;
        p = atomicAdd(&scanv[d4.x >> 7], 1);
        stage[p] = ((unsigned)s4.x << 7) | (unsigned)(d4.x & 127);
        p = atomicAdd(&scanv[d4.y >> 7], 1);
        stage[p] = ((unsigned)s4.y << 7) | (unsigned)(d4.y & 127);
        p = atomicAdd(&scanv[d4.z >> 7], 1);
        stage[p] = ((unsigned)s4.z << 7) | (unsigned)(d4.z & 127);
        p = atomicAdd(&scanv[d4.w >> 7], 1);
        stage[p] = ((unsigned)s4.w << 7) | (unsigned)(d4.w & 127);
    }
    __syncthreads();
    for (int i = t * 4; i < EPB; i += BSB * 4) {
        *(int4*)(binned + (size_t)blk * EPB + i) = *(const int4*)(stage + i);
        uchar4 w = make_uchar4((u8)(stage[i] & 127), (u8)(stage[i + 1] & 127),
                               (u8)(stage[i + 2] & 127), (u8)(stage[i + 3] & 127));
        *(uchar4*)(binned_b + (size_t)blk * EPB + i) = w;
    }
}

// ---------- consumer 1: degree + node1 (dinv, s) — byte stream, direct ----------
__global__ __launch_bounds__(BS) void k_deg_node1(
        const u8* __restrict__ binned_b, const unsigned* __restrict__ runinfo,
        const float* __restrict__ x, float* __restrict__ dinv,
        float* __restrict__ s) {
    __shared__ unsigned rinfo[NHB];
    __shared__ int cnt[4][136];
    int t = threadIdx.x, b = blockIdx.x;
    rinfo[t] = runinfo[(size_t)t * NB + b];
    for (int i = t; i < 4 * 136; i += BS) ((int*)cnt)[i] = 0;
    __syncthreads();
    int sg = t >> 4, lane = t & 15, rep = sg & 3;
#pragma unroll 4
    for (int k = 0; k < 16; ++k) {
        int r = sg * 16 + k;
        unsigned ri = rinfo[r];
        int off = (int)(ri & 0xFFFFu), c = (int)(ri >> 16);
        const u8* p = binned_b + (size_t)r * EPB + off;
        for (int j = lane; j < c; j += 16)
            atomicAdd(&cnt[rep][p[j]], 1);
    }
    __syncthreads();
    int node = b * 128 + t;
    if (t < 128 && node < N_NODES) {
        int d = cnt[0][t] + cnt[1][t] + cnt[2][t] + cnt[3][t];
        float di = rsqrtf((float)(d + 1));  // +1 self-loop
        dinv[node] = di;
        s[node] = di * x[node];
    }
}

// ---------- consumer 2: scatter1 + layer-1 MLP -> z ----------
__global__ __launch_bounds__(BS) void k_s1n2(
        const unsigned* __restrict__ binned, const unsigned* __restrict__ runinfo,
        const float* __restrict__ dinv, const float* __restrict__ s,
        const float* __restrict__ W1, const float* __restrict__ b1,
        const float* __restrict__ W2, float2* __restrict__ z) {
    __shared__ unsigned rinfo[NHB];
    __shared__ int incl[NHB];
    __shared__ alignas(16) unsigned stage[CAP];
    __shared__ float acc[4][136];
    __shared__ int fitStart;
    int t = threadIdx.x, b = blockIdx.x;
    unsigned ri = runinfo[(size_t)t * NB + b];
    rinfo[t] = ri;
    int c = (int)(ri >> 16);
    incl[t] = c;
    for (int i = t; i < 4 * 136; i += BS) ((float*)acc)[i] = 0.f;
    __syncthreads();
    for (int off = 1; off < BS; off <<= 1) {
        int u = (t >= off) ? incl[t - off] : 0;
        __syncthreads();
        incl[t] += u;
        __syncthreads();
    }
    if (t == BS - 1) fitStart = incl[t];
    __syncthreads();
    int lo = incl[t] - c;
    if (lo + c > CAP) atomicMin(&fitStart, lo);
    __syncthreads();
    // cooperative copy of fitting runs into stage
    int sg = t >> 4, lane = t & 15;
    for (int k = 0; k < 16; ++k) {
        int r = sg * 16 + k;
        unsigned rr = rinfo[r];
        int roff = (int)(rr & 0xFFFFu), rc = (int)(rr >> 16);
        int rlo = incl[r] - rc;
        if (rlo + rc > CAP) continue;
        const unsigned* p = binned + (size_t)r * EPB + roff;
        for (int j = lane; j < rc; j += 16) stage[rlo + j] = p[j];
    }
    __syncthreads();
    int fit = fitStart, rep = t & 3;
    int i = t;
    for (; i + 3 * BS < fit; i += 4 * BS) {
        unsigned r0 = stage[i], r1 = stage[i + BS], r2 = stage[i + 2 * BS],
                 r3 = stage[i + 3 * BS];
        float v0 = s[r0 >> 7], v1 = s[r1 >> 7], v2 = s[r2 >> 7], v3 = s[r3 >> 7];
        atomicAdd(&acc[rep][r0 & 127], v0);
        atomicAdd(&acc[rep][r1 & 127], v1);
        atomicAdd(&acc[rep][r2 & 127], v2);
        atomicAdd(&acc[rep][r3 & 127], v3);
    }
    for (; i < fit; i += BS) {
        unsigned rd = stage[i];
        atomicAdd(&acc[rep][rd & 127], s[rd >> 7]);
    }
    if (lo + c > CAP) {  // rare overflow: process own run from global
        const unsigned* p = binned + (size_t)t * EPB + (int)(rinfo[t] & 0xFFFFu);
        for (int j = 0; j < c; ++j) {
            unsigned rd = p[j];
            atomicAdd(&acc[rep][rd & 127], s[rd >> 7]);
        }
    }
    __syncthreads();
    int node = b * 128 + t;
    if (t < 128 && node < N_NODES) {
        float aggv = acc[0][t] + acc[1][t] + acc[2][t] + acc[3][t];
        float di = dinv[node];
        float a = di * (aggv + s[node]);
        float z0 = 0.f, z1 = 0.f;
#pragma unroll
        for (int f = 0; f < 16; ++f) {
            float h = fmaxf(a * W1[f] + b1[f], 0.f);
            z0 += h * W2[2 * f + 0];
            z1 += h * W2[2 * f + 1];
        }
        z[node] = make_float2(di * z0, di * z1);
    }
}

// ---------- consumer 3: scatter2 + epilogue -> out ----------
__global__ __launch_bounds__(BS) void k_s2out(
        const unsigned* __restrict__ binned, const unsigned* __restrict__ runinfo,
        const float* __restrict__ dinv, const float2* __restrict__ z,
        const float* __restrict__ b2, float2* __restrict__ out) {
    __shared__ unsigned rinfo[NHB];
    __shared__ int incl[NHB];
    __shared__ alignas(16) unsigned stage[CAP];
    __shared__ float accx[4][136], accy[4][136];
    __shared__ int fitStart;
    int t = threadIdx.x, b = blockIdx.x;
    unsigned ri = runinfo[(size_t)t * NB + b];
    rinfo[t] = ri;
    int c = (int)(ri >> 16);
    incl[t] = c;
    for (int i = t; i < 4 * 136; i += BS) {
        ((float*)accx)[i] = 0.f;
        ((float*)accy)[i] = 0.f;
    }
    __syncthreads();
    for (int off = 1; off < BS; off <<= 1) {
        int u = (t >= off) ? incl[t - off] : 0;
        __syncthreads();
        incl[t] += u;
        __syncthreads();
    }
    if (t == BS - 1) fitStart = incl[t];
    __syncthreads();
    int lo = incl[t] - c;
    if (lo + c > CAP) atomicMin(&fitStart, lo);
    __syncthreads();
    int sg = t >> 4, lane = t & 15;
    for (int k = 0; k < 16; ++k) {
        int r = sg * 16 + k;
        unsigned rr = rinfo[r];
        int roff = (int)(rr & 0xFFFFu), rc = (int)(rr >> 16);
        int rlo = incl[r] - rc;
        if (rlo + rc > CAP) continue;
        const unsigned* p = binned + (size_t)r * EPB + roff;
        for (int j = lane; j < rc; j += 16) stage[rlo + j] = p[j];
    }
    __syncthreads();
    int fit = fitStart, rep = t & 3;
    int i = t;
    for (; i + 3 * BS < fit; i += 4 * BS) {
        unsigned r0 = stage[i], r1 = stage[i + BS], r2 = stage[i + 2 * BS],
                 r3 = stage[i + 3 * BS];
        float2 z0 = z[r0 >> 7], z1 = z[r1 >> 7], z2 = z[r2 >> 7], z3 = z[r3 >> 7];
        atomicAdd(&accx[rep][r0 & 127], z0.x);
        atomicAdd(&accy[rep][r0 & 127], z0.y);
        atomicAdd(&accx[rep][r1 & 127], z1.x);
        atomicAdd(&accy[rep][r1 & 127], z1.y);
        atomicAdd(&accx[rep][r2 & 127], z2.x);
        atomicAdd(&accy[rep][r2 & 127], z2.y);
        atomicAdd(&accx[rep][r3 & 127], z3.x);
        atomicAdd(&accy[rep][r3 & 127], z3.y);
    }
    for (; i < fit; i += BS) {
        unsigned rd = stage[i];
        float2 zz = z[rd >> 7];
        atomicAdd(&accx[rep][rd & 127], zz.x);
        atomicAdd(&accy[rep][rd & 127], zz.y);
    }
    if (lo + c > CAP) {
        const unsigned* p = binned + (size_t)t * EPB + (int)(rinfo[t] & 0xFFFFu);
        for (int j = 0; j < c; ++j) {
            unsigned rd = p[j];
            float2 zz = z[rd >> 7];
            atomicAdd(&accx[rep][rd & 127], zz.x);
            atomicAdd(&accy[rep][rd & 127], zz.y);
        }
    }
    __syncthreads();
    int node = b * 128 + t;
    if (t < 128 && node < N_NODES) {
        float ax = accx[0][t] + accx[1][t] + accx[2][t] + accx[3][t];
        float ay = accy[0][t] + accy[1][t] + accy[2][t] + accy[3][t];
        float di = dinv[node];
        float2 zz = z[node];
        out[node] = make_float2(di * (ax + zz.x) + b2[0],
                                di * (ay + zz.y) + b2[1]);
    }
}

// ---------- fallback (device atomics), used only if ws too small ----------
__global__ void f_deg(const int* __restrict__ dst, int* __restrict__ deg) {
    int i = blockIdx.x * blockDim.x + threadIdx.x;
    if (i < N_EDGES) atomicAdd(&deg[dst[i]], 1);
}
__global__ void f_node1(const float* __restrict__ x, const int* __restrict__ deg,
                        float* __restrict__ dinv, float* __restrict__ s) {
    int v = blockIdx.x * blockDim.x + threadIdx.x;
    if (v < N_NODES) {
        float di = rsqrtf((float)(deg[v] + 1));
        dinv[v] = di;
        s[v] = di * x[v];
    }
}
__global__ void f_scatter1(const int* __restrict__ src, const int* __restrict__ dst,
                           const float* __restrict__ s, float* __restrict__ agg1) {
    int i = blockIdx.x * blockDim.x + threadIdx.x;
    if (i < N_EDGES) atomicAdd(&agg1[dst[i]], s[src[i]]);
}
__global__ void f_node2(const float* __restrict__ dinv, const float* __restrict__ s,
                        const float* __restrict__ agg1, const float* __restrict__ W1,
                        const float* __restrict__ b1, const float* __restrict__ W2,
                        float2* __restrict__ z) {
    int v = blockIdx.x * blockDim.x + threadIdx.x;
    if (v < N_NODES) {
        float di = dinv[v];
        float a = di * (agg1[v] + s[v]);
        float z0 = 0.f, z1 = 0.f;
#pragma unroll
        for (int f = 0; f < 16; ++f) {
            float h = fmaxf(a * W1[f] + b1[f], 0.f);
            z0 += h * W2[2 * f + 0];
            z1 += h * W2[2 * f + 1];
        }
        z[v] = make_float2(di * z0, di * z1);
    }
}
__global__ void f_scatter2(const int* __restrict__ src, const int* __restrict__ dst,
                           const float2* __restrict__ z, float* __restrict__ agg2) {
    int i = blockIdx.x * blockDim.x + threadIdx.x;
    if (i < N_EDGES) {
        float2 zz = z[src[i]];
        int d = dst[i];
        atomicAdd(&agg2[2 * d + 0], zz.x);
        atomicAdd(&agg2[2 * d + 1], zz.y);
    }
}
__global__ void f_out(const float* __restrict__ dinv, const float2* __restrict__ z,
                      const float2* __restrict__ agg2, const float* __restrict__ b2,
                      float2* __restrict__ out) {
    int v = blockIdx.x * blockDim.x + threadIdx.x;
    if (v < N_NODES) {
        float di = dinv[v];
        float2 a = agg2[v], zz = z[v];
        out[v] = make_float2(di * (a.x + zz.x) + b2[0], di * (a.y + zz.y) + b2[1]);
    }
}

// ---------- launch ----------
extern "C" void kernel_launch(void* const* d_in, const int* in_sizes, int n_in,
                              void* d_out, int out_size, void* d_ws, size_t ws_size,
                              hipStream_t stream) {
    const float* x  = (const float*)d_in[0];
    const int* eidx = (const int*)d_in[1];
    const float* W1 = (const float*)d_in[2];
    const float* b1 = (const float*)d_in[3];
    const float* W2 = (const float*)d_in[4];
    const float* b2 = (const float*)d_in[5];
    float* out = (float*)d_out;

    const int n = N_NODES;
    const int* src = eidx;
    const int* dst = eidx + N_EDGES;

    // workspace layout (32-bit words):
    // runinfo[NHB*NB] | binned[E] | binned_b[E/4] | dinv[n] | s[n] | z[2n]
    size_t oRun  = 0;
    size_t oBin  = oRun + (size_t)NHB * NB;
    size_t oBinB = oBin + N_EDGES;
    size_t oDinv = oBinB + N_EDGES / 4;
    size_t oS    = oDinv + n;
    size_t oZ    = oS + n;
    size_t need  = (oZ + 2 * n) * sizeof(int);

    if (ws_size >= need) {
        int* wsI = (int*)d_ws;
        unsigned* runinfo = (unsigned*)(wsI + oRun);
        unsigned* binned  = (unsigned*)(wsI + oBin);
        u8* binned_b      = (u8*)(wsI + oBinB);
        float* dinv = (float*)(wsI + oDinv);
        float* s    = (float*)(wsI + oS);
        float* z    = (float*)(wsI + oZ);

        k_bin2<<<NHB, BSB, 0, stream>>>(src, dst, binned, binned_b, runinfo);
        k_deg_node1<<<NB, BS, 0, stream>>>(binned_b, runinfo, x, dinv, s);
        k_s1n2<<<NB, BS, 0, stream>>>(binned, runinfo, dinv, s, W1, b1, W2,
                                      (float2*)z);
        k_s2out<<<NB, BS, 0, stream>>>(binned, runinfo, dinv, (const float2*)z,
                                       b2, (float2*)out);
    } else {
        float* ws = (float*)d_ws;
        int* deg    = (int*)ws;
        float* agg1 = ws + n;
        float* agg2 = ws + 2 * n;
        float* dinv = ws + 4 * n;
        float* s    = ws + 5 * n;
        float* z    = ws + 6 * n;
        (void)hipMemsetAsync(d_ws, 0, (size_t)(4 * n) * sizeof(float), stream);
        const int gridE = (N_EDGES + BS - 1) / BS;
        const int gridN = (n + BS - 1) / BS;
        f_deg<<<gridE, BS, 0, stream>>>(dst, deg);
        f_node1<<<gridN, BS, 0, stream>>>(x, deg, dinv, s);
        f_scatter1<<<gridE, BS, 0, stream>>>(src, dst, s, agg1);
        f_node2<<<gridN, BS, 0, stream>>>(dinv, s, agg1, W1, b1, W2, (float2*)z);
        f_scatter2<<<gridE, BS, 0, stream>>>(src, dst, (const float2*)z, agg2);
        f_out<<<gridN, BS, 0, stream>>>(dinv, (const float2*)z, (const float2*)agg2,
                                        b2, (float2*)out);
    }
}

// Round 8
// 116.741 us; speedup vs baseline: 1.0563x; 1.0563x over previous
//
#include <hip/hip_runtime.h>

#define N_NODES 100000
#define N_EDGES 3200000
#define NB 782               // buckets of 128 nodes
#define NBP 1024             // padded bins for scan
#define NHR 500              // binning blocks / regions
#define EPB (N_EDGES / NHR)  // 6400 edges per region (exact, mult of 4)
#define RS 8960              // region stride (words): 6400 + 3*782 pad = 8746 max
#define BSB 256              // binning block threads
#define BS 256               // consumer block threads
#define SENT 128u            // sentinel word: idx=128 (pad slot), src=0

typedef unsigned char u8;

// ---------- binning: per-block LDS counting sort, padded runs, linear flush ----
// binned region-major: region r owns binned[r*RS ..). Each bucket's run starts
// at a 4-word-aligned offset; pad slots hold SENT. packed = (src<<8)|(dst&127).
// runinfoT[b*NHR + r] = off | (nq<<16), nq = ceil(cnt/4) uint4-quads.
__global__ __launch_bounds__(BSB) void k_bin3(const int* __restrict__ src,
                                              const int* __restrict__ dst,
                                              unsigned* __restrict__ binned,
                                              u8* __restrict__ binned_b,
                                              unsigned* __restrict__ runinfoT) {
    __shared__ int hist[NBP];
    __shared__ int scanv[NBP];
    __shared__ int sh[BSB];
    __shared__ alignas(16) unsigned stage[RS];
    int t = threadIdx.x, blk = blockIdx.x;
    for (int i = t; i < NBP; i += BSB) hist[i] = 0;
    for (int i = t; i < RS; i += BSB) stage[i] = SENT;
    __syncthreads();
    int base = blk * EPB;
    for (int i = t * 4; i < EPB; i += BSB * 4) {
        int4 d = *(const int4*)(dst + base + i);
        atomicAdd(&hist[d.x >> 7], 1);
        atomicAdd(&hist[d.y >> 7], 1);
        atomicAdd(&hist[d.z >> 7], 1);
        atomicAdd(&hist[d.w >> 7], 1);
    }
    __syncthreads();
    // pad each bucket count to mult of 4; exclusive scan (thread owns 4 bins)
    int pp[4], v = 0;
#pragma unroll
    for (int j = 0; j < 4; ++j) {
        int c = hist[4 * t + j];
        pp[j] = (c + 3) & ~3;
        v += pp[j];
    }
    sh[t] = v;
    __syncthreads();
    for (int off = 1; off < BSB; off <<= 1) {
        int u = (t >= off) ? sh[t - off] : 0;
        __syncthreads();
        sh[t] += u;
        __syncthreads();
    }
    int run = sh[t] - v;
#pragma unroll
    for (int j = 0; j < 4; ++j) {
        scanv[4 * t + j] = run;
        run += pp[j];
    }
    __syncthreads();
    for (int b = t; b < NB; b += BSB)
        runinfoT[(size_t)b * NHR + blk] =
            (unsigned)scanv[b] | ((unsigned)((hist[b] + 3) >> 2) << 16);
    __syncthreads();
    // scatter into stage; scanv doubles as cursor
    for (int i = t * 4; i < EPB; i += BSB * 4) {
        int4 s4 = *(const int4*)(src + base + i);
        int4 d4 = *(const int4*)(dst + base + i);
        int p;
        p = atomicAdd(&scanv[d4.x >> 7], 1);
        stage[p] = ((unsigned)s4.x << 8) | (unsigned)(d4.x & 127);
        p = atomicAdd(&scanv[d4.y >> 7], 1);
        stage[p] = ((unsigned)s4.y << 8) | (unsigned)(d4.y & 127);
        p = atomicAdd(&scanv[d4.z >> 7], 1);
        stage[p] = ((unsigned)s4.z << 8) | (unsigned)(d4.z & 127);
        p = atomicAdd(&scanv[d4.w >> 7], 1);
        stage[p] = ((unsigned)s4.w << 8) | (unsigned)(d4.w & 127);
    }
    __syncthreads();
    // linear coalesced flush (words + low bytes)
    for (int i = t * 4; i < RS; i += BSB * 4) {
        *(int4*)(binned + (size_t)blk * RS + i) = *(const int4*)(stage + i);
        uchar4 w = make_uchar4((u8)(stage[i] & 255), (u8)(stage[i + 1] & 255),
                               (u8)(stage[i + 2] & 255), (u8)(stage[i + 3] & 255));
        *(uchar4*)(binned_b + (size_t)blk * RS + i) = w;
    }
}

// ---------- consumer 1: degree + node1 (dinv, s) — byte stream ----------
__global__ __launch_bounds__(BS) void k_deg_node1(
        const u8* __restrict__ binned_b, const unsigned* __restrict__ runinfoT,
        const float* __restrict__ x, float* __restrict__ dinv,
        float* __restrict__ s) {
    __shared__ int cnt[4][136];
    int t = threadIdx.x, b = blockIdx.x;
    for (int i = t; i < 4 * 136; i += BS) ((int*)cnt)[i] = 0;
    __syncthreads();
    int rep = t & 3;
    for (int r = t; r < NHR; r += BS) {
        unsigned ri = runinfoT[(size_t)b * NHR + r];
        int off = (int)(ri & 0xFFFFu), nq = (int)(ri >> 16);
        const uchar4* p = (const uchar4*)(binned_b + (size_t)r * RS + off);
        for (int q = 0; q < nq; ++q) {
            uchar4 w = p[q];
            atomicAdd(&cnt[rep][w.x], 1);
            atomicAdd(&cnt[rep][w.y], 1);
            atomicAdd(&cnt[rep][w.z], 1);
            atomicAdd(&cnt[rep][w.w], 1);
        }
    }
    __syncthreads();
    int node = b * 128 + t;
    if (t < 128 && node < N_NODES) {
        int d = cnt[0][t] + cnt[1][t] + cnt[2][t] + cnt[3][t];
        float di = rsqrtf((float)(d + 1));  // +1 self-loop; sentinels hit slot 128
        dinv[node] = di;
        s[node] = di * x[node];
    }
}

// ---------- consumer 2: scatter1 + layer-1 MLP -> z ----------
__global__ __launch_bounds__(BS) void k_s1n2(
        const unsigned* __restrict__ binned, const unsigned* __restrict__ runinfoT,
        const float* __restrict__ dinv, const float* __restrict__ s,
        const float* __restrict__ W1, const float* __restrict__ b1,
        const float* __restrict__ W2, float2* __restrict__ z) {
    __shared__ float acc[4][136];
    int t = threadIdx.x, b = blockIdx.x;
    for (int i = t; i < 4 * 136; i += BS) ((float*)acc)[i] = 0.f;
    __syncthreads();
    int rep = t & 3;
    for (int r = t; r < NHR; r += BS) {
        unsigned ri = runinfoT[(size_t)b * NHR + r];
        int off = (int)(ri & 0xFFFFu), nq = (int)(ri >> 16);
        const uint4* p = (const uint4*)(binned + (size_t)r * RS + off);
        for (int q = 0; q < nq; ++q) {
            uint4 w = p[q];
            float v0 = s[w.x >> 8], v1 = s[w.y >> 8];
            float v2 = s[w.z >> 8], v3 = s[w.w >> 8];
            atomicAdd(&acc[rep][w.x & 255], v0);
            atomicAdd(&acc[rep][w.y & 255], v1);
            atomicAdd(&acc[rep][w.z & 255], v2);
            atomicAdd(&acc[rep][w.w & 255], v3);
        }
    }
    __syncthreads();
    int node = b * 128 + t;
    if (t < 128 && node < N_NODES) {
        float aggv = acc[0][t] + acc[1][t] + acc[2][t] + acc[3][t];
        float di = dinv[node];
        float a = di * (aggv + s[node]);  // self-loop term
        float z0 = 0.f, z1 = 0.f;
#pragma unroll
        for (int f = 0; f < 16; ++f) {
            float h = fmaxf(a * W1[f] + b1[f], 0.f);
            z0 += h * W2[2 * f + 0];
            z1 += h * W2[2 * f + 1];
        }
        z[node] = make_float2(di * z0, di * z1);
    }
}

// ---------- consumer 3: scatter2 + epilogue -> out ----------
__global__ __launch_bounds__(BS) void k_s2out(
        const unsigned* __restrict__ binned, const unsigned* __restrict__ runinfoT,
        const float* __restrict__ dinv, const float2* __restrict__ z,
        const float* __restrict__ b2, float2* __restrict__ out) {
    __shared__ float accx[4][136], accy[4][136];
    int t = threadIdx.x, b = blockIdx.x;
    for (int i = t; i < 4 * 136; i += BS) {
        ((float*)accx)[i] = 0.f;
        ((float*)accy)[i] = 0.f;
    }
    __syncthreads();
    int rep = t & 3;
    for (int r = t; r < NHR; r += BS) {
        unsigned ri = runinfoT[(size_t)b * NHR + r];
        int off = (int)(ri & 0xFFFFu), nq = (int)(ri >> 16);
        const uint4* p = (const uint4*)(binned + (size_t)r * RS + off);
        for (int q = 0; q < nq; ++q) {
            uint4 w = p[q];
            float2 z0 = z[w.x >> 8], z1 = z[w.y >> 8];
            float2 z2 = z[w.z >> 8], z3 = z[w.w >> 8];
            atomicAdd(&accx[rep][w.x & 255], z0.x);
            atomicAdd(&accy[rep][w.x & 255], z0.y);
            atomicAdd(&accx[rep][w.y & 255], z1.x);
            atomicAdd(&accy[rep][w.y & 255], z1.y);
            atomicAdd(&accx[rep][w.z & 255], z2.x);
            atomicAdd(&accy[rep][w.z & 255], z2.y);
            atomicAdd(&accx[rep][w.w & 255], z3.x);
            atomicAdd(&accy[rep][w.w & 255], z3.y);
        }
    }
    __syncthreads();
    int node = b * 128 + t;
    if (t < 128 && node < N_NODES) {
        float ax = accx[0][t] + accx[1][t] + accx[2][t] + accx[3][t];
        float ay = accy[0][t] + accy[1][t] + accy[2][t] + accy[3][t];
        float di = dinv[node];
        float2 zz = z[node];
        out[node] = make_float2(di * (ax + zz.x) + b2[0],
                                di * (ay + zz.y) + b2[1]);
    }
}

// ---------- fallback (device atomics), used only if ws too small ----------
__global__ void f_deg(const int* __restrict__ dst, int* __restrict__ deg) {
    int i = blockIdx.x * blockDim.x + threadIdx.x;
    if (i < N_EDGES) atomicAdd(&deg[dst[i]], 1);
}
__global__ void f_node1(const float* __restrict__ x, const int* __restrict__ deg,
                        float* __restrict__ dinv, float* __restrict__ s) {
    int v = blockIdx.x * blockDim.x + threadIdx.x;
    if (v < N_NODES) {
        float di = rsqrtf((float)(deg[v] + 1));
        dinv[v] = di;
        s[v] = di * x[v];
    }
}
__global__ void f_scatter1(const int* __restrict__ src, const int* __restrict__ dst,
                           const float* __restrict__ s, float* __restrict__ agg1) {
    int i = blockIdx.x * blockDim.x + threadIdx.x;
    if (i < N_EDGES) atomicAdd(&agg1[dst[i]], s[src[i]]);
}
__global__ void f_node2(const float* __restrict__ dinv, const float* __restrict__ s,
                        const float* __restrict__ agg1, const float* __restrict__ W1,
                        const float* __restrict__ b1, const float* __restrict__ W2,
                        float2* __restrict__ z) {
    int v = blockIdx.x * blockDim.x + threadIdx.x;
    if (v < N_NODES) {
        float di = dinv[v];
        float a = di * (agg1[v] + s[v]);
        float z0 = 0.f, z1 = 0.f;
#pragma unroll
        for (int f = 0; f < 16; ++f) {
            float h = fmaxf(a * W1[f] + b1[f], 0.f);
            z0 += h * W2[2 * f + 0];
            z1 += h * W2[2 * f + 1];
        }
        z[v] = make_float2(di * z0, di * z1);
    }
}
__global__ void f_scatter2(const int* __restrict__ src, const int* __restrict__ dst,
                           const float2* __restrict__ z, float* __restrict__ agg2) {
    int i = blockIdx.x * blockDim.x + threadIdx.x;
    if (i < N_EDGES) {
        float2 zz = z[src[i]];
        int d = dst[i];
        atomicAdd(&agg2[2 * d + 0], zz.x);
        atomicAdd(&agg2[2 * d + 1], zz.y);
    }
}
__global__ void f_out(const float* __restrict__ dinv, const float2* __restrict__ z,
                      const float2* __restrict__ agg2, const float* __restrict__ b2,
                      float2* __restrict__ out) {
    int v = blockIdx.x * blockDim.x + threadIdx.x;
    if (v < N_NODES) {
        float di = dinv[v];
        float2 a = agg2[v], zz = z[v];
        out[v] = make_float2(di * (a.x + zz.x) + b2[0], di * (a.y + zz.y) + b2[1]);
    }
}

// ---------- launch ----------
extern "C" void kernel_launch(void* const* d_in, const int* in_sizes, int n_in,
                              void* d_out, int out_size, void* d_ws, size_t ws_size,
                              hipStream_t stream) {
    const float* x  = (const float*)d_in[0];
    const int* eidx = (const int*)d_in[1];
    const float* W1 = (const float*)d_in[2];
    const float* b1 = (const float*)d_in[3];
    const float* W2 = (const float*)d_in[4];
    const float* b2 = (const float*)d_in[5];
    float* out = (float*)d_out;

    const int n = N_NODES;
    const int* src = eidx;
    const int* dst = eidx + N_EDGES;

    // workspace layout (32-bit words):
    // runinfoT[NB*NHR] | binned[NHR*RS] | binned_b[NHR*RS/4] | dinv | s | z
    size_t oRun  = 0;
    size_t oBin  = oRun + (size_t)NB * NHR;
    size_t oBinB = oBin + (size_t)NHR * RS;
    size_t oDinv = oBinB + (size_t)NHR * RS / 4;
    size_t oS    = oDinv + n;
    size_t oZ    = oS + n;
    size_t need  = (oZ + 2 * n) * sizeof(int);

    if (ws_size >= need) {
        int* wsI = (int*)d_ws;
        unsigned* runinfoT = (unsigned*)(wsI + oRun);
        unsigned* binned   = (unsigned*)(wsI + oBin);
        u8* binned_b       = (u8*)(wsI + oBinB);
        float* dinv = (float*)(wsI + oDinv);
        float* s    = (float*)(wsI + oS);
        float* z    = (float*)(wsI + oZ);

        k_bin3<<<NHR, BSB, 0, stream>>>(src, dst, binned, binned_b, runinfoT);
        k_deg_node1<<<NB, BS, 0, stream>>>(binned_b, runinfoT, x, dinv, s);
        k_s1n2<<<NB, BS, 0, stream>>>(binned, runinfoT, dinv, s, W1, b1, W2,
                                      (float2*)z);
        k_s2out<<<NB, BS, 0, stream>>>(binned, runinfoT, dinv, (const float2*)z,
                                       b2, (float2*)out);
    } else {
        float* ws = (float*)d_ws;
        int* deg    = (int*)ws;
        float* agg1 = ws + n;
        float* agg2 = ws + 2 * n;
        float* dinv = ws + 4 * n;
        float* s    = ws + 5 * n;
        float* z    = ws + 6 * n;
        (void)hipMemsetAsync(d_ws, 0, (size_t)(4 * n) * sizeof(float), stream);
        const int gridE = (N_EDGES + BS - 1) / BS;
        const int gridN = (n + BS - 1) / BS;
        f_deg<<<gridE, BS, 0, stream>>>(dst, deg);
        f_node1<<<gridN, BS, 0, stream>>>(x, deg, dinv, s);
        f_scatter1<<<gridE, BS, 0, stream>>>(src, dst, s, agg1);
        f_node2<<<gridN, BS, 0, stream>>>(dinv, s, agg1, W1, b1, W2, (float2*)z);
        f_scatter2<<<gridE, BS, 0, stream>>>(src, dst, (const float2*)z, agg2);
        f_out<<<gridN, BS, 0, stream>>>(dinv, (const float2*)z, (const float2*)agg2,
                                        b2, (float2*)out);
    }
}

// Round 9
// 110.097 us; speedup vs baseline: 1.1200x; 1.0603x over previous
//
#include <hip/hip_runtime.h>

#define N_NODES 100000
#define NP 100096            // NB*128 padded node count
#define N_EDGES 3200000
#define NB 782               // buckets of 128 nodes
#define NBP 1024             // padded bins for scan
#define NHR 500              // binning blocks / regions
#define EPB (N_EDGES / NHR)  // 6400 edges per region (exact, mult of 4)
#define RS 8960              // region stride (words): 6400 + 3*782 pad <= 8746
#define BSB 512              // binning block threads
#define SPLIT 4              // region-split factor for consumer passes
#define RPB (NHR / SPLIT)    // 125 regions per consumer block
#define BSC 128              // consumer block threads (== nodes per bucket)
#define SENT 128u            // sentinel: idx=128 (pad slot), src=0

// ---------- binning: per-block LDS counting sort, padded runs, linear flush ----
// binned region-major: region r owns binned[r*RS ..). Bucket runs start at
// 4-word-aligned offsets; pads hold SENT. packed = (src<<8)|(dst&127).
// runinfoT[b*NHR + r] = off | (nq<<16), nq = ceil(cnt/4) uint4-quads.
__global__ __launch_bounds__(BSB) void k_bin3(const int* __restrict__ src,
                                              const int* __restrict__ dst,
                                              unsigned* __restrict__ binned,
                                              unsigned* __restrict__ runinfoT) {
    __shared__ int hist[NBP];
    __shared__ int scanv[NBP];
    __shared__ int sh[BSB];
    __shared__ alignas(16) unsigned stage[RS];
    int t = threadIdx.x, blk = blockIdx.x;
    for (int i = t; i < NBP; i += BSB) hist[i] = 0;
    for (int i = t; i < RS; i += BSB) stage[i] = SENT;
    __syncthreads();
    int base = blk * EPB;
    for (int i = t * 4; i < EPB; i += BSB * 4) {
        int4 d = *(const int4*)(dst + base + i);
        atomicAdd(&hist[d.x >> 7], 1);
        atomicAdd(&hist[d.y >> 7], 1);
        atomicAdd(&hist[d.z >> 7], 1);
        atomicAdd(&hist[d.w >> 7], 1);
    }
    __syncthreads();
    // pad counts to mult of 4; exclusive scan (each thread owns 2 bins)
    int c0 = hist[2 * t], c1 = hist[2 * t + 1];
    int p0 = (c0 + 3) & ~3, p1 = (c1 + 3) & ~3;
    int v = p0 + p1;
    sh[t] = v;
    __syncthreads();
    for (int off = 1; off < BSB; off <<= 1) {
        int u = (t >= off) ? sh[t - off] : 0;
        __syncthreads();
        sh[t] += u;
        __syncthreads();
    }
    int excl = sh[t] - v;
    scanv[2 * t] = excl;
    scanv[2 * t + 1] = excl + p0;
    __syncthreads();
    for (int b = t; b < NB; b += BSB)
        runinfoT[(size_t)b * NHR + blk] =
            (unsigned)scanv[b] | ((unsigned)((hist[b] + 3) >> 2) << 16);
    __syncthreads();
    // scatter into stage; scanv doubles as cursor
    for (int i = t * 4; i < EPB; i += BSB * 4) {
        int4 s4 = *(const int4*)(src + base + i);
        int4 d4 = *(const int4*)(dst + base + i);
        int p;
        p = atomicAdd(&scanv[d4.x >> 7], 1);
        stage[p] = ((unsigned)s4.x << 8) | (unsigned)(d4.x & 127);
        p = atomicAdd(&scanv[d4.y >> 7], 1);
        stage[p] = ((unsigned)s4.y << 8) | (unsigned)(d4.y & 127);
        p = atomicAdd(&scanv[d4.z >> 7], 1);
        stage[p] = ((unsigned)s4.z << 8) | (unsigned)(d4.z & 127);
        p = atomicAdd(&scanv[d4.w >> 7], 1);
        stage[p] = ((unsigned)s4.w << 8) | (unsigned)(d4.w & 127);
    }
    __syncthreads();
    for (int i = t * 4; i < RS; i += BSB * 4)
        *(int4*)(binned + (size_t)blk * RS + i) = *(const int4*)(stage + i);
}

// ---------- pass 1: partial degree (grid NB x SPLIT, 1 run / thread) ----------
__global__ __launch_bounds__(BSC) void k_degP(const unsigned* __restrict__ binned,
                                              const unsigned* __restrict__ runinfoT,
                                              int* __restrict__ degP) {
    __shared__ int cnt[4][136];
    int t = threadIdx.x, b = blockIdx.x, sp = blockIdx.y;
    for (int i = t; i < 4 * 136; i += BSC) ((int*)cnt)[i] = 0;
    __syncthreads();
    if (t < RPB) {
        int r = sp * RPB + t;
        unsigned ri = runinfoT[(size_t)b * NHR + r];
        int off = (int)(ri & 0xFFFFu), nq = (int)(ri >> 16);
        const uint4* p = (const uint4*)(binned + (size_t)r * RS + off);
        int rep = t & 3;
        int q = 0;
        for (; q + 1 < nq; q += 2) {
            uint4 w0 = p[q], w1 = p[q + 1];
            atomicAdd(&cnt[rep][w0.x & 255], 1);
            atomicAdd(&cnt[rep][w0.y & 255], 1);
            atomicAdd(&cnt[rep][w0.z & 255], 1);
            atomicAdd(&cnt[rep][w0.w & 255], 1);
            atomicAdd(&cnt[rep][w1.x & 255], 1);
            atomicAdd(&cnt[rep][w1.y & 255], 1);
            atomicAdd(&cnt[rep][w1.z & 255], 1);
            atomicAdd(&cnt[rep][w1.w & 255], 1);
        }
        if (q < nq) {
            uint4 w = p[q];
            atomicAdd(&cnt[rep][w.x & 255], 1);
            atomicAdd(&cnt[rep][w.y & 255], 1);
            atomicAdd(&cnt[rep][w.z & 255], 1);
            atomicAdd(&cnt[rep][w.w & 255], 1);
        }
    }
    __syncthreads();
    degP[(size_t)sp * NP + b * 128 + t] =
        cnt[0][t] + cnt[1][t] + cnt[2][t] + cnt[3][t];
}

// ---------- node pass 1: dinv, s ----------
__global__ __launch_bounds__(256) void k_node1(const int* __restrict__ degP,
                                               const float* __restrict__ x,
                                               float* __restrict__ dinv,
                                               float* __restrict__ s) {
    int v = blockIdx.x * 256 + threadIdx.x;
    if (v >= N_NODES) return;
    int d = 1 + degP[v] + degP[NP + v] + degP[2 * NP + v] + degP[3 * NP + v];
    float di = rsqrtf((float)d);
    dinv[v] = di;
    s[v] = di * x[v];
}

// ---------- pass 2: partial scatter1 ----------
__global__ __launch_bounds__(BSC) void k_s1P(const unsigned* __restrict__ binned,
                                             const unsigned* __restrict__ runinfoT,
                                             const float* __restrict__ s,
                                             float* __restrict__ aggP) {
    __shared__ float acc[4][136];
    int t = threadIdx.x, b = blockIdx.x, sp = blockIdx.y;
    for (int i = t; i < 4 * 136; i += BSC) ((float*)acc)[i] = 0.f;
    __syncthreads();
    if (t < RPB) {
        int r = sp * RPB + t;
        unsigned ri = runinfoT[(size_t)b * NHR + r];
        int off = (int)(ri & 0xFFFFu), nq = (int)(ri >> 16);
        const uint4* p = (const uint4*)(binned + (size_t)r * RS + off);
        int rep = t & 3;
        int q = 0;
        for (; q + 1 < nq; q += 2) {
            uint4 w0 = p[q], w1 = p[q + 1];
            float v0 = s[w0.x >> 8], v1 = s[w0.y >> 8];
            float v2 = s[w0.z >> 8], v3 = s[w0.w >> 8];
            float v4 = s[w1.x >> 8], v5 = s[w1.y >> 8];
            float v6 = s[w1.z >> 8], v7 = s[w1.w >> 8];
            atomicAdd(&acc[rep][w0.x & 255], v0);
            atomicAdd(&acc[rep][w0.y & 255], v1);
            atomicAdd(&acc[rep][w0.z & 255], v2);
            atomicAdd(&acc[rep][w0.w & 255], v3);
            atomicAdd(&acc[rep][w1.x & 255], v4);
            atomicAdd(&acc[rep][w1.y & 255], v5);
            atomicAdd(&acc[rep][w1.z & 255], v6);
            atomicAdd(&acc[rep][w1.w & 255], v7);
        }
        if (q < nq) {
            uint4 w = p[q];
            float v0 = s[w.x >> 8], v1 = s[w.y >> 8];
            float v2 = s[w.z >> 8], v3 = s[w.w >> 8];
            atomicAdd(&acc[rep][w.x & 255], v0);
            atomicAdd(&acc[rep][w.y & 255], v1);
            atomicAdd(&acc[rep][w.z & 255], v2);
            atomicAdd(&acc[rep][w.w & 255], v3);
        }
    }
    __syncthreads();
    aggP[(size_t)sp * NP + b * 128 + t] =
        acc[0][t] + acc[1][t] + acc[2][t] + acc[3][t];
}

// ---------- node pass 2: layer-1 MLP -> z ----------
__global__ __launch_bounds__(256) void k_node2(const float* __restrict__ aggP,
                                               const float* __restrict__ dinv,
                                               const float* __restrict__ s,
                                               const float* __restrict__ W1,
                                               const float* __restrict__ b1,
                                               const float* __restrict__ W2,
                                               float2* __restrict__ z) {
    int v = blockIdx.x * 256 + threadIdx.x;
    if (v >= N_NODES) return;
    float aggv = aggP[v] + aggP[NP + v] + aggP[2 * NP + v] + aggP[3 * NP + v];
    float di = dinv[v];
    float a = di * (aggv + s[v]);  // s[v] = self-loop term
    float z0 = 0.f, z1 = 0.f;
#pragma unroll
    for (int f = 0; f < 16; ++f) {
        float h = fmaxf(a * W1[f] + b1[f], 0.f);
        z0 += h * W2[2 * f + 0];
        z1 += h * W2[2 * f + 1];
    }
    z[v] = make_float2(di * z0, di * z1);
}

// ---------- pass 3: partial scatter2 ----------
__global__ __launch_bounds__(BSC) void k_s2P(const unsigned* __restrict__ binned,
                                             const unsigned* __restrict__ runinfoT,
                                             const float2* __restrict__ z,
                                             float2* __restrict__ agg2P) {
    __shared__ float accx[4][136], accy[4][136];
    int t = threadIdx.x, b = blockIdx.x, sp = blockIdx.y;
    for (int i = t; i < 4 * 136; i += BSC) {
        ((float*)accx)[i] = 0.f;
        ((float*)accy)[i] = 0.f;
    }
    __syncthreads();
    if (t < RPB) {
        int r = sp * RPB + t;
        unsigned ri = runinfoT[(size_t)b * NHR + r];
        int off = (int)(ri & 0xFFFFu), nq = (int)(ri >> 16);
        const uint4* p = (const uint4*)(binned + (size_t)r * RS + off);
        int rep = t & 3;
        int q = 0;
        for (; q + 1 < nq; q += 2) {
            uint4 w0 = p[q], w1 = p[q + 1];
            float2 z0 = z[w0.x >> 8], z1 = z[w0.y >> 8];
            float2 z2 = z[w0.z >> 8], z3 = z[w0.w >> 8];
            float2 z4 = z[w1.x >> 8], z5 = z[w1.y >> 8];
            float2 z6 = z[w1.z >> 8], z7 = z[w1.w >> 8];
            atomicAdd(&accx[rep][w0.x & 255], z0.x);
            atomicAdd(&accy[rep][w0.x & 255], z0.y);
            atomicAdd(&accx[rep][w0.y & 255], z1.x);
            atomicAdd(&accy[rep][w0.y & 255], z1.y);
            atomicAdd(&accx[rep][w0.z & 255], z2.x);
            atomicAdd(&accy[rep][w0.z & 255], z2.y);
            atomicAdd(&accx[rep][w0.w & 255], z3.x);
            atomicAdd(&accy[rep][w0.w & 255], z3.y);
            atomicAdd(&accx[rep][w1.x & 255], z4.x);
            atomicAdd(&accy[rep][w1.x & 255], z4.y);
            atomicAdd(&accx[rep][w1.y & 255], z5.x);
            atomicAdd(&accy[rep][w1.y & 255], z5.y);
            atomicAdd(&accx[rep][w1.z & 255], z6.x);
            atomicAdd(&accy[rep][w1.z & 255], z6.y);
            atomicAdd(&accx[rep][w1.w & 255], z7.x);
            atomicAdd(&accy[rep][w1.w & 255], z7.y);
        }
        if (q < nq) {
            uint4 w = p[q];
            float2 z0 = z[w.x >> 8], z1 = z[w.y >> 8];
            float2 z2 = z[w.z >> 8], z3 = z[w.w >> 8];
            atomicAdd(&accx[rep][w.x & 255], z0.x);
            atomicAdd(&accy[rep][w.x & 255], z0.y);
            atomicAdd(&accx[rep][w.y & 255], z1.x);
            atomicAdd(&accy[rep][w.y & 255], z1.y);
            atomicAdd(&accx[rep][w.z & 255], z2.x);
            atomicAdd(&accy[rep][w.z & 255], z2.y);
            atomicAdd(&accx[rep][w.w & 255], z3.x);
            atomicAdd(&accy[rep][w.w & 255], z3.y);
        }
    }
    __syncthreads();
    float ax = accx[0][t] + accx[1][t] + accx[2][t] + accx[3][t];
    float ay = accy[0][t] + accy[1][t] + accy[2][t] + accy[3][t];
    agg2P[(size_t)sp * NP + b * 128 + t] = make_float2(ax, ay);
}

// ---------- node pass 3: epilogue -> out ----------
__global__ __launch_bounds__(256) void k_out(const float2* __restrict__ agg2P,
                                             const float* __restrict__ dinv,
                                             const float2* __restrict__ z,
                                             const float* __restrict__ b2,
                                             float2* __restrict__ out) {
    int v = blockIdx.x * 256 + threadIdx.x;
    if (v >= N_NODES) return;
    float2 a0 = agg2P[v], a1 = agg2P[NP + v];
    float2 a2 = agg2P[2 * NP + v], a3 = agg2P[3 * NP + v];
    float2 zz = z[v];
    float ax = a0.x + a1.x + a2.x + a3.x + zz.x;
    float ay = a0.y + a1.y + a2.y + a3.y + zz.y;
    float di = dinv[v];
    out[v] = make_float2(di * ax + b2[0], di * ay + b2[1]);
}

// ---------- fallback (device atomics), used only if ws too small ----------
__global__ void f_deg(const int* __restrict__ dst, int* __restrict__ deg) {
    int i = blockIdx.x * blockDim.x + threadIdx.x;
    if (i < N_EDGES) atomicAdd(&deg[dst[i]], 1);
}
__global__ void f_node1(const float* __restrict__ x, const int* __restrict__ deg,
                        float* __restrict__ dinv, float* __restrict__ s) {
    int v = blockIdx.x * blockDim.x + threadIdx.x;
    if (v < N_NODES) {
        float di = rsqrtf((float)(deg[v] + 1));
        dinv[v] = di;
        s[v] = di * x[v];
    }
}
__global__ void f_scatter1(const int* __restrict__ src, const int* __restrict__ dst,
                           const float* __restrict__ s, float* __restrict__ agg1) {
    int i = blockIdx.x * blockDim.x + threadIdx.x;
    if (i < N_EDGES) atomicAdd(&agg1[dst[i]], s[src[i]]);
}
__global__ void f_node2(const float* __restrict__ dinv, const float* __restrict__ s,
                        const float* __restrict__ agg1, const float* __restrict__ W1,
                        const float* __restrict__ b1, const float* __restrict__ W2,
                        float2* __restrict__ z) {
    int v = blockIdx.x * blockDim.x + threadIdx.x;
    if (v < N_NODES) {
        float di = dinv[v];
        float a = di * (agg1[v] + s[v]);
        float z0 = 0.f, z1 = 0.f;
#pragma unroll
        for (int f = 0; f < 16; ++f) {
            float h = fmaxf(a * W1[f] + b1[f], 0.f);
            z0 += h * W2[2 * f + 0];
            z1 += h * W2[2 * f + 1];
        }
        z[v] = make_float2(di * z0, di * z1);
    }
}
__global__ void f_scatter2(const int* __restrict__ src, const int* __restrict__ dst,
                           const float2* __restrict__ z, float* __restrict__ agg2) {
    int i = blockIdx.x * blockDim.x + threadIdx.x;
    if (i < N_EDGES) {
        float2 zz = z[src[i]];
        int d = dst[i];
        atomicAdd(&agg2[2 * d + 0], zz.x);
        atomicAdd(&agg2[2 * d + 1], zz.y);
    }
}
__global__ void f_out(const float* __restrict__ dinv, const float2* __restrict__ z,
                      const float2* __restrict__ agg2, const float* __restrict__ b2,
                      float2* __restrict__ out) {
    int v = blockIdx.x * blockDim.x + threadIdx.x;
    if (v < N_NODES) {
        float di = dinv[v];
        float2 a = agg2[v], zz = z[v];
        out[v] = make_float2(di * (a.x + zz.x) + b2[0], di * (a.y + zz.y) + b2[1]);
    }
}

// ---------- launch ----------
extern "C" void kernel_launch(void* const* d_in, const int* in_sizes, int n_in,
                              void* d_out, int out_size, void* d_ws, size_t ws_size,
                              hipStream_t stream) {
    const float* x  = (const float*)d_in[0];
    const int* eidx = (const int*)d_in[1];
    const float* W1 = (const float*)d_in[2];
    const float* b1 = (const float*)d_in[3];
    const float* W2 = (const float*)d_in[4];
    const float* b2 = (const float*)d_in[5];
    float* out = (float*)d_out;

    const int n = N_NODES;
    const int* src = eidx;
    const int* dst = eidx + N_EDGES;

    // workspace layout (32-bit words):
    // runinfoT[NB*NHR] | binned[NHR*RS] | degP[4*NP] | aggP[4*NP] |
    // agg2P[8*NP] | dinv[NP] | s[NP] | z[2*NP]
    size_t oRun   = 0;
    size_t oBin   = oRun + (size_t)NB * NHR;
    size_t oDegP  = oBin + (size_t)NHR * RS;
    size_t oAggP  = oDegP + (size_t)SPLIT * NP;
    size_t oAgg2P = oAggP + (size_t)SPLIT * NP;
    size_t oDinv  = oAgg2P + (size_t)2 * SPLIT * NP;
    size_t oS     = oDinv + NP;
    size_t oZ     = oS + NP;
    size_t need   = (oZ + 2 * NP) * sizeof(int);

    if (ws_size >= need) {
        int* wsI = (int*)d_ws;
        unsigned* runinfoT = (unsigned*)(wsI + oRun);
        unsigned* binned   = (unsigned*)(wsI + oBin);
        int*   degP  = wsI + oDegP;
        float* aggP  = (float*)(wsI + oAggP);
        float2* agg2P = (float2*)(wsI + oAgg2P);
        float* dinv = (float*)(wsI + oDinv);
        float* s    = (float*)(wsI + oS);
        float2* z   = (float2*)(wsI + oZ);

        dim3 gridP(NB, SPLIT);
        k_bin3<<<NHR, BSB, 0, stream>>>(src, dst, binned, runinfoT);
        k_degP<<<gridP, BSC, 0, stream>>>(binned, runinfoT, degP);
        k_node1<<<NP / 256, 256, 0, stream>>>(degP, x, dinv, s);
        k_s1P<<<gridP, BSC, 0, stream>>>(binned, runinfoT, s, aggP);
        k_node2<<<NP / 256, 256, 0, stream>>>(aggP, dinv, s, W1, b1, W2, z);
        k_s2P<<<gridP, BSC, 0, stream>>>(binned, runinfoT, z, agg2P);
        k_out<<<NP / 256, 256, 0, stream>>>(agg2P, dinv, z, b2, (float2*)out);
    } else {
        float* ws = (float*)d_ws;
        int* deg    = (int*)ws;
        float* agg1 = ws + n;
        float* agg2 = ws + 2 * n;
        float* dinv = ws + 4 * n;
        float* s    = ws + 5 * n;
        float* z    = ws + 6 * n;
        (void)hipMemsetAsync(d_ws, 0, (size_t)(4 * n) * sizeof(float), stream);
        const int gridE = (N_EDGES + 255) / 256;
        const int gridN = (n + 255) / 256;
        f_deg<<<gridE, 256, 0, stream>>>(dst, deg);
        f_node1<<<gridN, 256, 0, stream>>>(x, deg, dinv, s);
        f_scatter1<<<gridE, 256, 0, stream>>>(src, dst, s, agg1);
        f_node2<<<gridN, 256, 0, stream>>>(dinv, s, agg1, W1, b1, W2, (float2*)z);
        f_scatter2<<<gridE, 256, 0, stream>>>(src, dst, (const float2*)z, agg2);
        f_out<<<gridN, 256, 0, stream>>>(dinv, (const float2*)z, (const float2*)agg2,
                                         b2, (float2*)out);
    }
}

// Round 10
// 99.480 us; speedup vs baseline: 1.2396x; 1.1067x over previous
//
#include <hip/hip_runtime.h>

#define N_NODES 100000
#define NP 100096            // NB*128 padded node count
#define N_EDGES 3200000
#define NB 782               // buckets of 128 nodes
#define NBP 1024             // padded bins for scan
#define NHR 500              // binning blocks / regions
#define EPB (N_EDGES / NHR)  // 6400 edges per region (exact, mult of 4)
#define RS 8960              // region stride (words): 6400 + 3*782 pad <= 8746
#define BSB 512              // binning block threads
#define SPLIT 4              // region-split factor for consumer passes
#define RPB (NHR / SPLIT)    // 125 regions per consumer block
#define BSC 128              // consumer block threads (== nodes per bucket)
#define NWG (NB * SPLIT)     // 3128 consumer blocks = 8 * 391 (exact)
#define CHUNK (NWG / 8)      // 391 consecutive logical blocks per XCD
#define SENT 128u            // sentinel: idx=128 (pad slot), src=0

typedef unsigned char u8;

// XCD-chunked swizzle: physical blocks round-robin XCDs (phys%8); give XCD k
// a CONTIGUOUS range of logical ids so adjacent buckets share that XCD's L2.
__device__ __forceinline__ void decode_bs(unsigned phys, int& b, int& sp) {
    unsigned L = (phys & 7u) * CHUNK + (phys >> 3);
    sp = (int)(L / NB);
    b  = (int)(L - (unsigned)sp * NB);
}

// ---------- binning: per-block LDS counting sort, padded runs, linear flush ----
// binned region-major: region r owns binned[r*RS ..). Bucket runs start at
// 4-word-aligned offsets; pads hold SENT. packed = (src<<8)|(dst&127).
// binned_b = low byte (dst&127 or 128 sentinel).
// runinfoT[b*NHR + r] = off | (nq<<16), nq = ceil(cnt/4) quads.
__global__ __launch_bounds__(BSB) void k_bin3(const int* __restrict__ src,
                                              const int* __restrict__ dst,
                                              unsigned* __restrict__ binned,
                                              u8* __restrict__ binned_b,
                                              unsigned* __restrict__ runinfoT) {
    __shared__ int hist[NBP];
    __shared__ int scanv[NBP];
    __shared__ int sh[BSB];
    __shared__ alignas(16) unsigned stage[RS];
    int t = threadIdx.x, blk = blockIdx.x;
    for (int i = t; i < NBP; i += BSB) hist[i] = 0;
    for (int i = t; i < RS; i += BSB) stage[i] = SENT;
    __syncthreads();
    int base = blk * EPB;
    for (int i = t * 4; i < EPB; i += BSB * 4) {
        int4 d = *(const int4*)(dst + base + i);
        atomicAdd(&hist[d.x >> 7], 1);
        atomicAdd(&hist[d.y >> 7], 1);
        atomicAdd(&hist[d.z >> 7], 1);
        atomicAdd(&hist[d.w >> 7], 1);
    }
    __syncthreads();
    // pad counts to mult of 4; exclusive scan (each thread owns 2 bins)
    int c0 = hist[2 * t], c1 = hist[2 * t + 1];
    int p0 = (c0 + 3) & ~3, p1 = (c1 + 3) & ~3;
    int v = p0 + p1;
    sh[t] = v;
    __syncthreads();
    for (int off = 1; off < BSB; off <<= 1) {
        int u = (t >= off) ? sh[t - off] : 0;
        __syncthreads();
        sh[t] += u;
        __syncthreads();
    }
    int excl = sh[t] - v;
    scanv[2 * t] = excl;
    scanv[2 * t + 1] = excl + p0;
    __syncthreads();
    for (int b = t; b < NB; b += BSB)
        runinfoT[(size_t)b * NHR + blk] =
            (unsigned)scanv[b] | ((unsigned)((hist[b] + 3) >> 2) << 16);
    __syncthreads();
    // scatter into stage; scanv doubles as cursor
    for (int i = t * 4; i < EPB; i += BSB * 4) {
        int4 s4 = *(const int4*)(src + base + i);
        int4 d4 = *(const int4*)(dst + base + i);
        int p;
        p = atomicAdd(&scanv[d4.x >> 7], 1);
        stage[p] = ((unsigned)s4.x << 8) | (unsigned)(d4.x & 127);
        p = atomicAdd(&scanv[d4.y >> 7], 1);
        stage[p] = ((unsigned)s4.y << 8) | (unsigned)(d4.y & 127);
        p = atomicAdd(&scanv[d4.z >> 7], 1);
        stage[p] = ((unsigned)s4.z << 8) | (unsigned)(d4.z & 127);
        p = atomicAdd(&scanv[d4.w >> 7], 1);
        stage[p] = ((unsigned)s4.w << 8) | (unsigned)(d4.w & 127);
    }
    __syncthreads();
    for (int i = t * 4; i < RS; i += BSB * 4) {
        *(int4*)(binned + (size_t)blk * RS + i) = *(const int4*)(stage + i);
        uchar4 w = make_uchar4((u8)(stage[i] & 255), (u8)(stage[i + 1] & 255),
                               (u8)(stage[i + 2] & 255), (u8)(stage[i + 3] & 255));
        *(uchar4*)(binned_b + (size_t)blk * RS + i) = w;
    }
}

// ---------- pass 1: partial degree (byte stream, 1 run / thread) ----------
__global__ __launch_bounds__(BSC) void k_degP(const u8* __restrict__ binned_b,
                                              const unsigned* __restrict__ runinfoT,
                                              int* __restrict__ degP) {
    __shared__ int cnt[4][136];
    int t = threadIdx.x;
    int b, sp;
    decode_bs(blockIdx.x, b, sp);
    for (int i = t; i < 4 * 136; i += BSC) ((int*)cnt)[i] = 0;
    __syncthreads();
    if (t < RPB) {
        int r = sp * RPB + t;
        unsigned ri = runinfoT[(size_t)b * NHR + r];
        int off = (int)(ri & 0xFFFFu), nq = (int)(ri >> 16);
        const uchar4* p = (const uchar4*)(binned_b + (size_t)r * RS + off);
        int rep = t & 3;
        int q = 0;
        for (; q + 1 < nq; q += 2) {
            uchar4 w0 = p[q], w1 = p[q + 1];
            atomicAdd(&cnt[rep][w0.x], 1);
            atomicAdd(&cnt[rep][w0.y], 1);
            atomicAdd(&cnt[rep][w0.z], 1);
            atomicAdd(&cnt[rep][w0.w], 1);
            atomicAdd(&cnt[rep][w1.x], 1);
            atomicAdd(&cnt[rep][w1.y], 1);
            atomicAdd(&cnt[rep][w1.z], 1);
            atomicAdd(&cnt[rep][w1.w], 1);
        }
        if (q < nq) {
            uchar4 w = p[q];
            atomicAdd(&cnt[rep][w.x], 1);
            atomicAdd(&cnt[rep][w.y], 1);
            atomicAdd(&cnt[rep][w.z], 1);
            atomicAdd(&cnt[rep][w.w], 1);
        }
    }
    __syncthreads();
    degP[(size_t)sp * NP + b * 128 + t] =
        cnt[0][t] + cnt[1][t] + cnt[2][t] + cnt[3][t];
}

// ---------- node pass 1: dinv, s ----------
__global__ __launch_bounds__(256) void k_node1(const int* __restrict__ degP,
                                               const float* __restrict__ x,
                                               float* __restrict__ dinv,
                                               float* __restrict__ s) {
    int v = blockIdx.x * 256 + threadIdx.x;
    if (v >= N_NODES) return;
    int d = 1 + degP[v] + degP[NP + v] + degP[2 * NP + v] + degP[3 * NP + v];
    float di = rsqrtf((float)d);
    dinv[v] = di;
    s[v] = di * x[v];
}

// ---------- pass 2: partial scatter1 ----------
__global__ __launch_bounds__(BSC) void k_s1P(const unsigned* __restrict__ binned,
                                             const unsigned* __restrict__ runinfoT,
                                             const float* __restrict__ s,
                                             float* __restrict__ aggP) {
    __shared__ float acc[4][136];
    int t = threadIdx.x;
    int b, sp;
    decode_bs(blockIdx.x, b, sp);
    for (int i = t; i < 4 * 136; i += BSC) ((float*)acc)[i] = 0.f;
    __syncthreads();
    if (t < RPB) {
        int r = sp * RPB + t;
        unsigned ri = runinfoT[(size_t)b * NHR + r];
        int off = (int)(ri & 0xFFFFu), nq = (int)(ri >> 16);
        const uint4* p = (const uint4*)(binned + (size_t)r * RS + off);
        int rep = t & 3;
        int q = 0;
        for (; q + 1 < nq; q += 2) {
            uint4 w0 = p[q], w1 = p[q + 1];
            float v0 = s[w0.x >> 8], v1 = s[w0.y >> 8];
            float v2 = s[w0.z >> 8], v3 = s[w0.w >> 8];
            float v4 = s[w1.x >> 8], v5 = s[w1.y >> 8];
            float v6 = s[w1.z >> 8], v7 = s[w1.w >> 8];
            atomicAdd(&acc[rep][w0.x & 255], v0);
            atomicAdd(&acc[rep][w0.y & 255], v1);
            atomicAdd(&acc[rep][w0.z & 255], v2);
            atomicAdd(&acc[rep][w0.w & 255], v3);
            atomicAdd(&acc[rep][w1.x & 255], v4);
            atomicAdd(&acc[rep][w1.y & 255], v5);
            atomicAdd(&acc[rep][w1.z & 255], v6);
            atomicAdd(&acc[rep][w1.w & 255], v7);
        }
        if (q < nq) {
            uint4 w = p[q];
            float v0 = s[w.x >> 8], v1 = s[w.y >> 8];
            float v2 = s[w.z >> 8], v3 = s[w.w >> 8];
            atomicAdd(&acc[rep][w.x & 255], v0);
            atomicAdd(&acc[rep][w.y & 255], v1);
            atomicAdd(&acc[rep][w.z & 255], v2);
            atomicAdd(&acc[rep][w.w & 255], v3);
        }
    }
    __syncthreads();
    aggP[(size_t)sp * NP + b * 128 + t] =
        acc[0][t] + acc[1][t] + acc[2][t] + acc[3][t];
}

// ---------- node pass 2: layer-1 MLP -> z ----------
__global__ __launch_bounds__(256) void k_node2(const float* __restrict__ aggP,
                                               const float* __restrict__ dinv,
                                               const float* __restrict__ s,
                                               const float* __restrict__ W1,
                                               const float* __restrict__ b1,
                                               const float* __restrict__ W2,
                                               float2* __restrict__ z) {
    int v = blockIdx.x * 256 + threadIdx.x;
    if (v >= N_NODES) return;
    float aggv = aggP[v] + aggP[NP + v] + aggP[2 * NP + v] + aggP[3 * NP + v];
    float di = dinv[v];
    float a = di * (aggv + s[v]);  // s[v] = self-loop term
    float z0 = 0.f, z1 = 0.f;
#pragma unroll
    for (int f = 0; f < 16; ++f) {
        float h = fmaxf(a * W1[f] + b1[f], 0.f);
        z0 += h * W2[2 * f + 0];
        z1 += h * W2[2 * f + 1];
    }
    z[v] = make_float2(di * z0, di * z1);
}

// ---------- pass 3: partial scatter2 ----------
__global__ __launch_bounds__(BSC) void k_s2P(const unsigned* __restrict__ binned,
                                             const unsigned* __restrict__ runinfoT,
                                             const float2* __restrict__ z,
                                             float2* __restrict__ agg2P) {
    __shared__ float accx[4][136], accy[4][136];
    int t = threadIdx.x;
    int b, sp;
    decode_bs(blockIdx.x, b, sp);
    for (int i = t; i < 4 * 136; i += BSC) {
        ((float*)accx)[i] = 0.f;
        ((float*)accy)[i] = 0.f;
    }
    __syncthreads();
    if (t < RPB) {
        int r = sp * RPB + t;
        unsigned ri = runinfoT[(size_t)b * NHR + r];
        int off = (int)(ri & 0xFFFFu), nq = (int)(ri >> 16);
        const uint4* p = (const uint4*)(binned + (size_t)r * RS + off);
        int rep = t & 3;
        int q = 0;
        for (; q + 1 < nq; q += 2) {
            uint4 w0 = p[q], w1 = p[q + 1];
            float2 z0 = z[w0.x >> 8], z1 = z[w0.y >> 8];
            float2 z2 = z[w0.z >> 8], z3 = z[w0.w >> 8];
            float2 z4 = z[w1.x >> 8], z5 = z[w1.y >> 8];
            float2 z6 = z[w1.z >> 8], z7 = z[w1.w >> 8];
            atomicAdd(&accx[rep][w0.x & 255], z0.x);
            atomicAdd(&accy[rep][w0.x & 255], z0.y);
            atomicAdd(&accx[rep][w0.y & 255], z1.x);
            atomicAdd(&accy[rep][w0.y & 255], z1.y);
            atomicAdd(&accx[rep][w0.z & 255], z2.x);
            atomicAdd(&accy[rep][w0.z & 255], z2.y);
            atomicAdd(&accx[rep][w0.w & 255], z3.x);
            atomicAdd(&accy[rep][w0.w & 255], z3.y);
            atomicAdd(&accx[rep][w1.x & 255], z4.x);
            atomicAdd(&accy[rep][w1.x & 255], z4.y);
            atomicAdd(&accx[rep][w1.y & 255], z5.x);
            atomicAdd(&accy[rep][w1.y & 255], z5.y);
            atomicAdd(&accx[rep][w1.z & 255], z6.x);
            atomicAdd(&accy[rep][w1.z & 255], z6.y);
            atomicAdd(&accx[rep][w1.w & 255], z7.x);
            atomicAdd(&accy[rep][w1.w & 255], z7.y);
        }
        if (q < nq) {
            uint4 w = p[q];
            float2 z0 = z[w.x >> 8], z1 = z[w.y >> 8];
            float2 z2 = z[w.z >> 8], z3 = z[w.w >> 8];
            atomicAdd(&accx[rep][w.x & 255], z0.x);
            atomicAdd(&accy[rep][w.x & 255], z0.y);
            atomicAdd(&accx[rep][w.y & 255], z1.x);
            atomicAdd(&accy[rep][w.y & 255], z1.y);
            atomicAdd(&accx[rep][w.z & 255], z2.x);
            atomicAdd(&accy[rep][w.z & 255], z2.y);
            atomicAdd(&accx[rep][w.w & 255], z3.x);
            atomicAdd(&accy[rep][w.w & 255], z3.y);
        }
    }
    __syncthreads();
    float ax = accx[0][t] + accx[1][t] + accx[2][t] + accx[3][t];
    float ay = accy[0][t] + accy[1][t] + accy[2][t] + accy[3][t];
    agg2P[(size_t)sp * NP + b * 128 + t] = make_float2(ax, ay);
}

// ---------- node pass 3: epilogue -> out ----------
__global__ __launch_bounds__(256) void k_out(const float2* __restrict__ agg2P,
                                             const float* __restrict__ dinv,
                                             const float2* __restrict__ z,
                                             const float* __restrict__ b2,
                                             float2* __restrict__ out) {
    int v = blockIdx.x * 256 + threadIdx.x;
    if (v >= N_NODES) return;
    float2 a0 = agg2P[v], a1 = agg2P[NP + v];
    float2 a2 = agg2P[2 * NP + v], a3 = agg2P[3 * NP + v];
    float2 zz = z[v];
    float ax = a0.x + a1.x + a2.x + a3.x + zz.x;
    float ay = a0.y + a1.y + a2.y + a3.y + zz.y;
    float di = dinv[v];
    out[v] = make_float2(di * ax + b2[0], di * ay + b2[1]);
}

// ---------- fallback (device atomics), used only if ws too small ----------
__global__ void f_deg(const int* __restrict__ dst, int* __restrict__ deg) {
    int i = blockIdx.x * blockDim.x + threadIdx.x;
    if (i < N_EDGES) atomicAdd(&deg[dst[i]], 1);
}
__global__ void f_node1(const float* __restrict__ x, const int* __restrict__ deg,
                        float* __restrict__ dinv, float* __restrict__ s) {
    int v = blockIdx.x * blockDim.x + threadIdx.x;
    if (v < N_NODES) {
        float di = rsqrtf((float)(deg[v] + 1));
        dinv[v] = di;
        s[v] = di * x[v];
    }
}
__global__ void f_scatter1(const int* __restrict__ src, const int* __restrict__ dst,
                           const float* __restrict__ s, float* __restrict__ agg1) {
    int i = blockIdx.x * blockDim.x + threadIdx.x;
    if (i < N_EDGES) atomicAdd(&agg1[dst[i]], s[src[i]]);
}
__global__ void f_node2(const float* __restrict__ dinv, const float* __restrict__ s,
                        const float* __restrict__ agg1, const float* __restrict__ W1,
                        const float* __restrict__ b1, const float* __restrict__ W2,
                        float2* __restrict__ z) {
    int v = blockIdx.x * blockDim.x + threadIdx.x;
    if (v < N_NODES) {
        float di = dinv[v];
        float a = di * (agg1[v] + s[v]);
        float z0 = 0.f, z1 = 0.f;
#pragma unroll
        for (int f = 0; f < 16; ++f) {
            float h = fmaxf(a * W1[f] + b1[f], 0.f);
            z0 += h * W2[2 * f + 0];
            z1 += h * W2[2 * f + 1];
        }
        z[v] = make_float2(di * z0, di * z1);
    }
}
__global__ void f_scatter2(const int* __restrict__ src, const int* __restrict__ dst,
                           const float2* __restrict__ z, float* __restrict__ agg2) {
    int i = blockIdx.x * blockDim.x + threadIdx.x;
    if (i < N_EDGES) {
        float2 zz = z[src[i]];
        int d = dst[i];
        atomicAdd(&agg2[2 * d + 0], zz.x);
        atomicAdd(&agg2[2 * d + 1], zz.y);
    }
}
__global__ void f_out(const float* __restrict__ dinv, const float2* __restrict__ z,
                      const float2* __restrict__ agg2, const float* __restrict__ b2,
                      float2* __restrict__ out) {
    int v = blockIdx.x * blockDim.x + threadIdx.x;
    if (v < N_NODES) {
        float di = dinv[v];
        float2 a = agg2[v], zz = z[v];
        out[v] = make_float2(di * (a.x + zz.x) + b2[0], di * (a.y + zz.y) + b2[1]);
    }
}

// ---------- launch ----------
extern "C" void kernel_launch(void* const* d_in, const int* in_sizes, int n_in,
                              void* d_out, int out_size, void* d_ws, size_t ws_size,
                              hipStream_t stream) {
    const float* x  = (const float*)d_in[0];
    const int* eidx = (const int*)d_in[1];
    const float* W1 = (const float*)d_in[2];
    const float* b1 = (const float*)d_in[3];
    const float* W2 = (const float*)d_in[4];
    const float* b2 = (const float*)d_in[5];
    float* out = (float*)d_out;

    const int n = N_NODES;
    const int* src = eidx;
    const int* dst = eidx + N_EDGES;

    // workspace layout (32-bit words):
    // runinfoT[NB*NHR] | binned[NHR*RS] | binned_b[NHR*RS/4] | degP[4*NP] |
    // aggP[4*NP] | agg2P[8*NP] | dinv[NP] | s[NP] | z[2*NP]
    size_t oRun   = 0;
    size_t oBin   = oRun + (size_t)NB * NHR;
    size_t oBinB  = oBin + (size_t)NHR * RS;
    size_t oDegP  = oBinB + (size_t)NHR * RS / 4;
    size_t oAggP  = oDegP + (size_t)SPLIT * NP;
    size_t oAgg2P = oAggP + (size_t)SPLIT * NP;
    size_t oDinv  = oAgg2P + (size_t)2 * SPLIT * NP;
    size_t oS     = oDinv + NP;
    size_t oZ     = oS + NP;
    size_t need   = (oZ + 2 * NP) * sizeof(int);

    if (ws_size >= need) {
        int* wsI = (int*)d_ws;
        unsigned* runinfoT = (unsigned*)(wsI + oRun);
        unsigned* binned   = (unsigned*)(wsI + oBin);
        u8* binned_b       = (u8*)(wsI + oBinB);
        int*   degP  = wsI + oDegP;
        float* aggP  = (float*)(wsI + oAggP);
        float2* agg2P = (float2*)(wsI + oAgg2P);
        float* dinv = (float*)(wsI + oDinv);
        float* s    = (float*)(wsI + oS);
        float2* z   = (float2*)(wsI + oZ);

        k_bin3<<<NHR, BSB, 0, stream>>>(src, dst, binned, binned_b, runinfoT);
        k_degP<<<NWG, BSC, 0, stream>>>(binned_b, runinfoT, degP);
        k_node1<<<NP / 256, 256, 0, stream>>>(degP, x, dinv, s);
        k_s1P<<<NWG, BSC, 0, stream>>>(binned, runinfoT, s, aggP);
        k_node2<<<NP / 256, 256, 0, stream>>>(aggP, dinv, s, W1, b1, W2, z);
        k_s2P<<<NWG, BSC, 0, stream>>>(binned, runinfoT, z, agg2P);
        k_out<<<NP / 256, 256, 0, stream>>>(agg2P, dinv, z, b2, (float2*)out);
    } else {
        float* ws = (float*)d_ws;
        int* deg    = (int*)ws;
        float* agg1 = ws + n;
        float* agg2 = ws + 2 * n;
        float* dinv = ws + 4 * n;
        float* s    = ws + 5 * n;
        float* z    = ws + 6 * n;
        (void)hipMemsetAsync(d_ws, 0, (size_t)(4 * n) * sizeof(float), stream);
        const int gridE = (N_EDGES + 255) / 256;
        const int gridN = (n + 255) / 256;
        f_deg<<<gridE, 256, 0, stream>>>(dst, deg);
        f_node1<<<gridN, 256, 0, stream>>>(x, deg, dinv, s);
        f_scatter1<<<gridE, 256, 0, stream>>>(src, dst, s, agg1);
        f_node2<<<gridN, 256, 0, stream>>>(dinv, s, agg1, W1, b1, W2, (float2*)z);
        f_scatter2<<<gridE, 256, 0, stream>>>(src, dst, (const float2*)z, agg2);
        f_out<<<gridN, 256, 0, stream>>>(dinv, (const float2*)z, (const float2*)agg2,
                                         b2, (float2*)out);
    }
}